// Round 1
// baseline (216.645 us; speedup 1.0000x reference)
//
#include <hip/hip_runtime.h>

// out[b,c,i,j] = x[b,c,i,j] * (i%3!=0) * (j%3!=0)
// Derivation: the fold scatter-add targets exactly the coords the unfold read,
// so the composite is an elementwise 0/1 mask, separable in i and j:
// zero iff (idx+PAD)%3==1, i.e. idx%3==0.
//
// Each thread handles 2 consecutive float4 = 32B = one half-row (row = 32
// floats = 128B). Thread t: row i = (t>>2)&31, col base j0 = (t&3)*8.
// Rows with i%3==0 are all-zero: store zeros, skip the load entirely
// (rows are 128B-aligned segments, so skipped rows cost no HBM fetch).
// Non-temporal loads/stores: zero reuse, keep L2 clean.
// NOTE: __builtin_nontemporal_* needs a true vector type, not HIP_vector_type.

typedef float vf4 __attribute__((ext_vector_type(4)));

constexpr int N_TOTAL = 64 * 512 * 32 * 32;   // 33,554,432 floats
constexpr int NT      = N_TOTAL / 8;          // 4,194,304 threads (2 float4 each)

__global__ __launch_bounds__(256) void unfoldfold_mask_kernel(
    const vf4* __restrict__ x, vf4* __restrict__ out) {
    int t = blockIdx.x * blockDim.x + threadIdx.x;   // grid sized exactly
    int i = (t >> 2) & 31;                           // row within 32x32 image
    int idx = t * 2;                                 // float4 index
    if ((i % 3) == 0) {
        vf4 z = (vf4)(0.f);
        __builtin_nontemporal_store(z, &out[idx]);
        __builtin_nontemporal_store(z, &out[idx + 1]);
        return;
    }
    vf4 a = __builtin_nontemporal_load(&x[idx]);
    vf4 b = __builtin_nontemporal_load(&x[idx + 1]);
    // j0 = (t&3)*8; j0 % 3 selects which lanes of the 8-float group are zeroed
    int m = ((t & 3) << 3) % 3;
    // lanes l in [0,8): zero iff (j0+l)%3==0
    if (m == 0)      { a.x = 0.f; a.w = 0.f; b.z = 0.f; }        // l=0,3,6
    else if (m == 1) { a.z = 0.f; b.y = 0.f; }                   // l=2,5
    else             { a.y = 0.f; b.x = 0.f; b.w = 0.f; }        // l=1,4,7
    __builtin_nontemporal_store(a, &out[idx]);
    __builtin_nontemporal_store(b, &out[idx + 1]);
}

extern "C" void kernel_launch(void* const* d_in, const int* in_sizes, int n_in,
                              void* d_out, int out_size, void* d_ws, size_t ws_size,
                              hipStream_t stream) {
    const vf4* x = (const vf4*)d_in[0];
    vf4* out = (vf4*)d_out;
    unfoldfold_mask_kernel<<<NT / 256, 256, 0, stream>>>(x, out);
}

// Round 2
// 209.054 us; speedup vs baseline: 1.0363x; 1.0363x over previous
//
#include <hip/hip_runtime.h>

// out[b,c,i,j] = x[b,c,i,j] * (i%3!=0) * (j%3!=0)
// The unfold->fold composite is an elementwise separable 0/1 mask (see prior
// rounds): zero iff i%3==0 or j%3==0.
//
// R1 change: ONE float4 per thread (was 2 consecutive float4s/thread).
// The old layout put consecutive lanes at 32B stride within each memory
// instruction -> every 64B cacheline was half-covered per instruction,
// doubling L1/L2 transactions on both the load and store streams.
// Now lane l accesses a contiguous 16B slot: each wave instruction covers
// a dense 1KB segment -> minimal transaction count, fill-kernel-like BW.
//
// Rows with i%3==0 (11 of 32) are all-zero: store zeros, skip the load
// (rows are 128B-aligned segments, so skipped rows cost no HBM fetch).
// Non-temporal: the harness's 512MiB poison fill flushes L2/L3 between
// iterations, so there is no reuse to cache; keep the streams clean.

typedef float vf4 __attribute__((ext_vector_type(4)));

constexpr int N_TOTAL = 64 * 512 * 32 * 32;   // 33,554,432 floats
constexpr int N_F4    = N_TOTAL / 4;          // 8,388,608 float4s

__global__ __launch_bounds__(256) void unfoldfold_mask_kernel(
    const vf4* __restrict__ x, vf4* __restrict__ out) {
    int q = blockIdx.x * blockDim.x + threadIdx.x;   // float4 index; grid exact
    int i = (q >> 3) & 31;                           // row within 32x32 image
    if ((i % 3) == 0) {
        vf4 z = (vf4)(0.f);
        __builtin_nontemporal_store(z, &out[q]);
        return;
    }
    vf4 a = __builtin_nontemporal_load(&x[q]);
    // j0 = (q&7)*4; element e (j = j0+e) is zeroed iff (j0+e)%3==0.
    // (q&7)*4 mod 3 == (q&7) mod 3.
    int m = (q & 7) % 3;
    if (m == 0)      { a.x = 0.f; a.w = 0.f; }   // e=0,3
    else if (m == 1) { a.z = 0.f; }              // e=2
    else             { a.y = 0.f; }              // e=1
    __builtin_nontemporal_store(a, &out[q]);
}

extern "C" void kernel_launch(void* const* d_in, const int* in_sizes, int n_in,
                              void* d_out, int out_size, void* d_ws, size_t ws_size,
                              hipStream_t stream) {
    const vf4* x = (const vf4*)d_in[0];
    vf4* out = (vf4*)d_out;
    unfoldfold_mask_kernel<<<N_F4 / 256, 256, 0, stream>>>(x, out);
}